// Round 8
// baseline (910.042 us; speedup 1.0000x reference)
//
#include <hip/hip_runtime.h>

// R13: slice_kernel de-scattered + de-atomicized (conv/final/pad = R12 best).
//  - W-overlay into xmid: was 64 scalar f16 global stores/thread (2B scatter,
//    G13 violation). Now staged per-wave in LDS [16][72] f16 tile and stored
//    as coalesced f16x8 (128 B per token row). 8 vector stores/thread.
//  - ST/norm accumulation: was 2M global f32 atomicAdds (64-deep contention)
//    + memset. Now non-atomic per-chunk partials STp[512][4096]/snormp[512][64]
//    written coalesced; attn_pt reduces the 64 chunks itself (1 MB/block).
//    STp/snormp alias the padx region (dead after conv within each batch).
//    hipMemsetAsync dispatches deleted.
// Per-batch workspace (total 154,012,672 B):
//   padx  f16 [258][258][128]  @ 0           (17,040,384)
//     STp   f32 [512][4096]    @ 0           ( 8,388,608)  aliases padx
//     snormp f32 [512][64]     @ 8,388,608   (   131,072)  aliases padx
//   wcat  f16 [9][1024][128]   @ 17,040,384  ( 2,359,296)
//   PT    f16 [128][512]       @ 19,663,872  (   131,072)
//   xmid  f16 [65536][512]     @ 19,794,944  (67,108,864)
//   fxT   f16 [512][65536]     @ 86,903,808  (67,108,864)

typedef _Float16 f16;
typedef _Float16 f16x8 __attribute__((ext_vector_type(8)));
typedef _Float16 f16x4 __attribute__((ext_vector_type(4)));
typedef float    f32x4 __attribute__((ext_vector_type(4)));

static const size_t OFF_PADX = 0;
static const size_t OFF_STP  = 0;            // aliases padx (dead after conv)
static const size_t OFF_SNP  = 8388608;      // aliases padx
static const size_t OFF_WCAT = 17040384;
static const size_t OFF_PT   = 19663872;
static const size_t OFF_XMID = 19794944;
static const size_t OFF_FXT  = 86903808;

__device__ __forceinline__ void ldsdma16(f16* lds, const f16* g) {
  __builtin_amdgcn_global_load_lds((__attribute__((address_space(1))) void*)g,
                                   (__attribute__((address_space(3))) void*)lds,
                                   16, 0, 0);
}

// ---------------------------------------------------------------- pad + cast x
__global__ __launch_bounds__(256) void pad_kernel(const float* __restrict__ xb,
                                                  f16* __restrict__ padx) {
  int idx = blockIdx.x * 256 + threadIdx.x;           // over [258][258][16]
  if (idx >= 258 * 258 * 16) return;
  int c8 = (idx & 15) * 8;
  int r  = idx >> 4;                                  // ip*258 + jp
  int jp = r % 258;
  int ip = r / 258;
  f16x8 v;
  if (ip == 0 || ip == 257 || jp == 0 || jp == 257) {
#pragma unroll
    for (int j = 0; j < 8; ++j) v[j] = (f16)0.0f;
  } else {
    const float* src = xb + ((size_t)(ip - 1) * 256 + (jp - 1)) * 128 + c8;
#pragma unroll
    for (int j = 0; j < 8; ++j) v[j] = (f16)src[j];
  }
  *(f16x8*)(padx + (size_t)r * 128 + c8) = v;
}

// ------------------------------------------- weights: Wcat_T[tap][co(1024)][ci]
__global__ __launch_bounds__(256) void prepw_kernel(const float* __restrict__ Wfx,
                                                    const float* __restrict__ Wx,
                                                    f16* __restrict__ wcat) {
  int idx = blockIdx.x * 256 + threadIdx.x;           // (tap*1024+co)*128+ci
  if (idx >= 9 * 1024 * 128) return;
  int ci = idx & 127;
  int t  = idx >> 7;
  int co = t & 1023;
  int tap = t >> 10;
  float v = (co < 512) ? Wfx[(size_t)(tap * 128 + ci) * 512 + co]
                       : Wx[(size_t)(tap * 128 + ci) * 512 + (co - 512)];
  wcat[idx] = (f16)v;
}

// --------------------------------------------------- fused conv: implicit GEMM
// 18-phase pipeline on R9 geometry + XCD-chunked block swizzle (R11).
__global__ __launch_bounds__(256, 2) void conv_kernel(const f16* __restrict__ padx,
                                                      const f16* __restrict__ wcat,
                                                      const float* __restrict__ bfx,
                                                      const float* __restrict__ bx,
                                                      f16* __restrict__ xmid,
                                                      f16* __restrict__ fxT) {
  __shared__ f16 smem[33024];        // 66,048 B total
  f16* As0 = smem;                   // [130][64] swizzled: slot rr*64 + (c^(rr&7))*8
  f16* As1 = smem + 8320;
  f16* Bs0 = smem + 16640;           // [128][64] same swizzle
  f16* Bs1 = smem + 24832;
  int tid = threadIdx.x;
  // XCD-chunked swizzle (bijective: 4096 % 8 == 0)
  int wg = (blockIdx.x & 7) * 512 + (blockIdx.x >> 3);
  int nt = wg & 7;
  int mt = wg >> 3;                  // 0..511
  int i  = mt >> 1;
  int j0 = (mt & 1) * 128;
  int n0 = nt * 128;
  int lane = tid & 63, wave = tid >> 6;
  int ln15 = lane & 15, quad = lane >> 4;
  int wm = wave & 1, wn = wave >> 1;

  f32x4 acc[4][4] = {};

  auto stageA = [&](int di, int kc, f16* dst) {   // 130 rows x 8 chunks = 1040 slots
#pragma unroll
    for (int ph = 0; ph < 5; ++ph) {
      int s = ph * 256 + tid;
      if (ph < 4 || s < 1040) {
        int rr = s >> 3;
        int qq = ((s & 7) ^ (rr & 7)) * 8;
        ldsdma16(&dst[(ph * 256 + wave * 64) * 8],
                 padx + ((size_t)(i + di) * 258 + j0 + rr) * 128 + kc + qq);
      }
    }
  };
  auto stageB = [&](int tap, int kc, f16* dst) {  // 128 rows x 8 chunks = 1024 slots
#pragma unroll
    for (int ph = 0; ph < 4; ++ph) {
      int s = ph * 256 + tid;
      int rr = s >> 3;
      int qq = ((s & 7) ^ (rr & 7)) * 8;
      ldsdma16(&dst[(ph * 256 + wave * 64) * 8],
               wcat + ((size_t)(tap * 1024 + n0 + rr)) * 128 + kc + qq);
    }
  };
  auto computePhase = [&](int dj, const f16* A, const f16* B) {
#pragma unroll
    for (int ks = 0; ks < 2; ++ks) {
      int q = ks * 4 + quad;         // 0..7 k-chunk within plane
      f16x8 af[4], bfr[4];
#pragma unroll
      for (int xx = 0; xx < 4; ++xx) {
        int t  = dj + wm * 64 + xx * 16 + ln15;
        int rb = wn * 64 + xx * 16 + ln15;
        af[xx]  = *(const f16x8*)(&A[t * 64 + ((q ^ (t & 7)) * 8)]);
        bfr[xx] = *(const f16x8*)(&B[rb * 64 + ((q ^ (rb & 7)) * 8)]);
      }
      __builtin_amdgcn_s_setprio(1);
#pragma unroll
      for (int mf = 0; mf < 4; ++mf)
#pragma unroll
        for (int nf = 0; nf < 4; ++nf)
          acc[mf][nf] = __builtin_amdgcn_mfma_f32_16x16x32_f16(af[mf], bfr[nf],
                                                               acc[mf][nf], 0, 0, 0);
      __builtin_amdgcn_s_setprio(0);
    }
  };

  // ---- prologue: first A plane + first B plane
  stageA(0, 0, As0);
  stageB(0, 0, Bs0);
  __syncthreads();

  // ---- 18 phases: p = di*6 + kc2*3 + dj (all decode constant under unroll)
#pragma unroll
  for (int p = 0; p < 18; ++p) {
    int dj   = p % 3;
    int dikc = p / 3;
    if (p + 1 < 18) {
      int np = p + 1;
      int ndj = np % 3, ndikc = np / 3;
      int ndi = ndikc >> 1, nkc = (ndikc & 1) * 64;
      stageB(ndi * 3 + ndj, nkc, (np & 1) ? Bs1 : Bs0);
      if (ndj == 0) stageA(ndi, nkc, (ndikc & 1) ? As1 : As0);
    }
    computePhase(dj, (dikc & 1) ? As1 : As0, (p & 1) ? Bs1 : Bs0);
    __syncthreads();
  }

  size_t token0 = (size_t)i * 256 + j0;
  if (nt < 4) {
    // ---- fxT path: bias, transpose through LDS, f16x8 coalesced stores
    f16* tile = smem;                // [col 128][token 128] stride 136 (34,816 B)
#pragma unroll
    for (int nf = 0; nf < 4; ++nf) {
      int colLoc = wn * 64 + nf * 16 + ln15;
      float bias = bfx[n0 + colLoc];
#pragma unroll
      for (int mf = 0; mf < 4; ++mf) {
        int tokBase = wm * 64 + mf * 16 + quad * 4;
        f16x4 pk;
#pragma unroll
        for (int v = 0; v < 4; ++v) pk[v] = (f16)(acc[mf][nf][v] + bias);
        *(f16x4*)(&tile[colLoc * 136 + tokBase]) = pk;
      }
    }
    __syncthreads();
#pragma unroll
    for (int it2 = 0; it2 < 8; ++it2) {
      int s = it2 * 256 + tid;       // 0..2047
      int c = s >> 4, t8 = s & 15;
      f16x8 vv = *(const f16x8*)(&tile[c * 136 + t8 * 8]);
      *(f16x8*)(fxT + (size_t)(n0 + c) * 65536 + token0 + t8 * 8) = vv;
    }
  } else {
    // ---- xmid path: token-major rows
#pragma unroll
    for (int nf = 0; nf < 4; ++nf) {
      int col = n0 + wn * 64 + nf * 16 + ln15;
      float bias = bx[col - 512];
#pragma unroll
      for (int mf = 0; mf < 4; ++mf) {
        int rbase = wm * 64 + mf * 16 + quad * 4;
#pragma unroll
        for (int v = 0; v < 4; ++v)
          xmid[(size_t)(token0 + rbase + v) * 512 + (col - 512)] =
              (f16)(acc[mf][nf][v] + bias);
      }
    }
  }
}

// ---------------- slice: MFMA logits -> shfl softmax -> W overlay + MFMA ST acc
// R13: overlay writes LDS-staged + coalesced f16x8; ST/norm partials non-atomic.
#define WS_S 72
#define WT_S 264
__global__ __launch_bounds__(256, 2) void slice_kernel(f16* __restrict__ xmid,
                                                       const f16* __restrict__ fxT,
                                                       const float* __restrict__ Wslice,
                                                       const float* __restrict__ bslice,
                                                       const float* __restrict__ temperature,
                                                       float* __restrict__ STp,
                                                       float* __restrict__ snormp) {
  __shared__ f16 Ws[64 * WS_S];      // [g][d] f16, padded
  __shared__ f16 Wt[64 * WT_S];      // [g][t_local 256] padded, wave-private t-stripes
  __shared__ float red[64 * 65];     // cross-wave ST reduction
  __shared__ float redn[64];
  __shared__ __align__(16) f16 wtile[4 * 16 * 72];  // per-wave [16 tok][72] overlay tile
  int tid = threadIdx.x;
  int h = blockIdx.x >> 6;           // 8
  int chunk = blockIdx.x & 63;       // 64 chunks of 1024 tokens
  int tok0 = chunk * 1024;
  int lane = tid & 63, wave = tid >> 6;
  int ln15 = lane & 15, quad = lane >> 4;
  f16* wt = wtile + wave * (16 * 72);

  for (int s = tid; s < 4096; s += 256)
    Ws[(s >> 6) * WS_S + (s & 63)] = (f16)Wslice[s];
  if (tid < 64) redn[tid] = 0.f;
  float tc = temperature[h];
  tc = fminf(fmaxf(tc, 0.1f), 5.0f);
  float invt = 1.0f / tc;
  float bsv[4];
#pragma unroll
  for (int nf = 0; nf < 4; ++nf) bsv[nf] = bslice[nf * 16 + ln15];
  __syncthreads();

  f32x4 acc2[4][4] = {};             // ST partial: [mf->g][nf->d]
  float naccv[4] = {};               // norm partial per nf (g = nf*16+ln15)

  for (int it = 0; it < 4; ++it) {
    int tsub = it * 256 + wave * 64;            // this wave's 64 tokens (local)
    // ---- phase A: logits via MFMA (A direct from global, B from LDS Ws)
    f32x4 accA[4][4] = {};
#pragma unroll
    for (int kq = 0; kq < 2; ++kq) {
      f16x8 bf[4];
#pragma unroll
      for (int nf = 0; nf < 4; ++nf)
        bf[nf] = *(const f16x8*)(&Ws[(nf * 16 + ln15) * WS_S + kq * 32 + quad * 8]);
#pragma unroll
      for (int mf = 0; mf < 4; ++mf) {
        f16x8 af = *(const f16x8*)(xmid + (size_t)(tok0 + tsub + mf * 16 + ln15) * 512 +
                                   h * 64 + kq * 32 + quad * 8);
#pragma unroll
        for (int nf = 0; nf < 4; ++nf)
          accA[mf][nf] = __builtin_amdgcn_mfma_f32_16x16x32_f16(af, bf[nf], accA[mf][nf],
                                                                0, 0, 0);
      }
    }
    // ---- softmax over g; stage overlay in wave-private LDS tile + Wt
#pragma unroll
    for (int mf = 0; mf < 4; ++mf) {
#pragma unroll
      for (int v = 0; v < 4; ++v) {
        float l[4];
#pragma unroll
        for (int nf = 0; nf < 4; ++nf) l[nf] = (accA[mf][nf][v] + bsv[nf]) * invt;
        float lm = fmaxf(fmaxf(l[0], l[1]), fmaxf(l[2], l[3]));
#pragma unroll
        for (int off = 1; off < 16; off <<= 1) lm = fmaxf(lm, __shfl_xor(lm, off, 64));
        float e[4], ssum = 0.f;
#pragma unroll
        for (int nf = 0; nf < 4; ++nf) { e[nf] = __expf(l[nf] - lm); ssum += e[nf]; }
#pragma unroll
        for (int off = 1; off < 16; off <<= 1) ssum += __shfl_xor(ssum, off, 64);
        float winv = 1.0f / ssum;
        int t_str = wave * 64 + mf * 16 + quad * 4 + v;  // local to 256-stripe set
#pragma unroll
        for (int nf = 0; nf < 4; ++nf) {
          float w = e[nf] * winv;
          naccv[nf] += w;
          f16 wh = (f16)w;
          wt[(quad * 4 + v) * 72 + nf * 16 + ln15] = wh;
          Wt[(nf * 16 + ln15) * WT_S + t_str] = wh;
        }
      }
      // coalesced overlay store: 16 token rows x 128 B (wave-private tile)
#pragma unroll
      for (int k = 0; k < 2; ++k) {
        int s = k * 64 + lane;
        int t8 = s >> 3, c8 = s & 7;
        f16x8 vv = *(const f16x8*)(&wt[t8 * 72 + c8 * 8]);
        *(f16x8*)(xmid + (size_t)(tok0 + tsub + mf * 16 + t8) * 512 + h * 64 + c8 * 8) = vv;
      }
    }
    // ---- phase B: acc2[g][d] += Wt^T-frag x fxT-frag (wave-private k-range)
#pragma unroll
    for (int kq = 0; kq < 2; ++kq) {
      int kof = wave * 64 + kq * 32 + quad * 8;          // within 256-stripe set
      f16x8 bfB[4];
#pragma unroll
      for (int nf = 0; nf < 4; ++nf)
        bfB[nf] = *(const f16x8*)(fxT + (size_t)(h * 64 + nf * 16 + ln15) * 65536 +
                                  tok0 + it * 256 + kof);
#pragma unroll
      for (int mf = 0; mf < 4; ++mf) {
        f16x8 afB = *(const f16x8*)(&Wt[(mf * 16 + ln15) * WT_S + kof]);
#pragma unroll
        for (int nf = 0; nf < 4; ++nf)
          acc2[mf][nf] = __builtin_amdgcn_mfma_f32_16x16x32_f16(afB, bfB[nf],
                                                                acc2[mf][nf], 0, 0, 0);
      }
    }
  }

  // ---- norm partials into LDS (16 contributors per g)
#pragma unroll
  for (int nf = 0; nf < 4; ++nf) atomicAdd(&redn[nf * 16 + ln15], naccv[nf]);

  // ---- cross-wave ST reduce, then non-atomic per-chunk partial writes
  for (int s = 0; s < 4; ++s) {
    if (wave == s) {
#pragma unroll
      for (int mf = 0; mf < 4; ++mf)
#pragma unroll
        for (int nf = 0; nf < 4; ++nf)
#pragma unroll
          for (int v = 0; v < 4; ++v) {
            int g = mf * 16 + quad * 4 + v;
            int d = nf * 16 + ln15;
            if (s == 0) red[g * 65 + d] = acc2[mf][nf][v];
            else        red[g * 65 + d] += acc2[mf][nf][v];
          }
    }
    __syncthreads();
  }
  float* stp = STp + ((size_t)h * 64 + chunk) * 4096;
  for (int s2 = tid; s2 < 4096; s2 += 256)
    stp[s2] = red[(s2 >> 6) * 65 + (s2 & 63)];
  if (tid < 64) snormp[((size_t)h * 64 + chunk) * 64 + tid] = redn[tid];
}

// --------- merged attn + PT fold; first reduces the 64 per-chunk partials
__global__ __launch_bounds__(256) void attn_pt_kernel(const float* __restrict__ STp,
                                                      const float* __restrict__ snormp,
                                                      const float* __restrict__ Wq,
                                                      const float* __restrict__ Wk,
                                                      const float* __restrict__ Wv,
                                                      const float* __restrict__ Wout,
                                                      f16* __restrict__ PT) {
  int h = blockIdx.x;                // 8
  __shared__ float tok[64 * 65];     // aliased as scores later
  __shared__ float qs[64 * 65];
  __shared__ float ksm[64 * 65];     // aliased as out_slice later
  __shared__ f16 vsm[64 * 65];
  __shared__ float sn[64];
  int tid = threadIdx.x;
  const float* sp = STp + (size_t)h * 64 * 4096;
  const float* np = snormp + (size_t)h * 64 * 64;
  if (tid < 64) {
    float a = 0.f;
    for (int c = 0; c < 64; ++c) a += np[c * 64 + tid];
    sn[tid] = a;
  }
  __syncthreads();
  for (int s = tid; s < 4096; s += 256) {
    float a = 0.f;
#pragma unroll 8
    for (int c = 0; c < 64; ++c) a += sp[(size_t)c * 4096 + s];
    tok[(s >> 6) * 65 + (s & 63)] = a / (sn[s >> 6] + 1e-5f);
  }
  __syncthreads();
  int g = tid >> 2, p16 = (tid & 3) * 16;
  for (int e0 = 0; e0 < 16; ++e0) {
    int e = p16 + e0;
    const float* wq = Wq + e * 64;
    const float* wk = Wk + e * 64;
    const float* wv = Wv + e * 64;
    float aq = 0, ak = 0, av = 0;
#pragma unroll 8
    for (int d = 0; d < 64; ++d) {
      float tv = tok[g * 65 + d];
      aq += tv * wq[d];
      ak += tv * wk[d];
      av += tv * wv[d];
    }
    qs[g * 65 + e] = aq;
    ksm[g * 65 + e] = ak;
    vsm[g * 65 + e] = (f16)av;
  }
  __syncthreads();
  float* sc = tok;  // alias, tok dead
  for (int f0 = 0; f0 < 16; ++f0) {
    int f = p16 + f0;
    float s = 0;
#pragma unroll 8
    for (int e = 0; e < 64; ++e) s += qs[g * 65 + e] * ksm[f * 65 + e];
    sc[g * 65 + f] = s * 0.125f;
  }
  __syncthreads();
  if (tid < 64) {
    float m = -1e30f;
    for (int f = 0; f < 64; ++f) m = fmaxf(m, sc[tid * 65 + f]);
    float ssum = 0;
    for (int f = 0; f < 64; ++f) {
      float e = __expf(sc[tid * 65 + f] - m);
      sc[tid * 65 + f] = e;
      ssum += e;
    }
    float inv = 1.0f / ssum;
    for (int f = 0; f < 64; ++f) sc[tid * 65 + f] *= inv;
  }
  __syncthreads();
  // out_slice -> os LDS (overwrite ksm; dead after scores)
  float* os = ksm;
  for (int e0 = 0; e0 < 16; ++e0) {
    int e = p16 + e0;
    float o = 0;
#pragma unroll 8
    for (int f = 0; f < 64; ++f) o += sc[g * 65 + f] * (float)vsm[f * 65 + e];
    os[g * 65 + e] = o;
  }
  __syncthreads();
  // ---- PT fold (os from LDS)
  int o = tid >> 1, gh = (tid & 1) * 32;
  const float* wr = Wout + (size_t)o * 512 + h * 64;
  float wreg[64];
#pragma unroll
  for (int d = 0; d < 64; ++d) wreg[d] = wr[d];
  for (int gg = 0; gg < 32; ++gg) {
    int gI = gh + gg;
    float s = 0;
#pragma unroll
    for (int d = 0; d < 64; ++d) s += os[gI * 65 + d] * wreg[d];
    PT[(size_t)o * 512 + h * 64 + gI] = (f16)s;
  }
}

// -------------------- final: out[n,o] = sum_k W[n,k] * PT[o,k] + bout[o]
// R5 structure (32 KB LDS -> 5 blocks/CU; occupancy > pipelining for streaming).
__global__ __launch_bounds__(256, 2) void final_kernel(const f16* __restrict__ xmid,
                                                       const f16* __restrict__ PT,
                                                       const float* __restrict__ bout,
                                                       float* __restrict__ outb) {
  __shared__ f16 As[128 * 64];
  __shared__ f16 Bs[128 * 64];
  int tid = threadIdx.x;
  int tok0 = blockIdx.x << 7;        // 512 blocks
  int lane = tid & 63, wave = tid >> 6;
  int ln15 = lane & 15, quad = lane >> 4;
  int wm = wave & 1, wn = wave >> 1;
  int rr[4], qq8[4];
#pragma unroll
  for (int ph = 0; ph < 4; ++ph) {
    int s = ph * 256 + tid;
    rr[ph] = s >> 3;
    qq8[ph] = ((s & 7) ^ (rr[ph] & 7)) * 8;
  }
  int wbase = wave * 512;
  f32x4 acc[4][4] = {};
  const f16* aB = xmid + (size_t)tok0 * 512;
  const f16* bB = PT;
  for (int kc = 0; kc < 512; kc += 64) {
#pragma unroll
    for (int ph = 0; ph < 4; ++ph) {
      ldsdma16(&As[ph * 2048 + wbase], aB + (size_t)rr[ph] * 512 + kc + qq8[ph]);
      ldsdma16(&Bs[ph * 2048 + wbase], bB + (size_t)rr[ph] * 512 + kc + qq8[ph]);
    }
    __syncthreads();
#pragma unroll
    for (int ks = 0; ks < 2; ++ks) {
      f16x8 af[4], bfr[4];
      int q = ks * 4 + quad;
#pragma unroll
      for (int xx = 0; xx < 4; ++xx) {
        int ra = wm * 64 + xx * 16 + ln15;
        int rb = wn * 64 + xx * 16 + ln15;
        af[xx]  = *(const f16x8*)(&As[ra * 64 + (q ^ (ra & 7)) * 8]);
        bfr[xx] = *(const f16x8*)(&Bs[rb * 64 + (q ^ (rb & 7)) * 8]);
      }
#pragma unroll
      for (int mf = 0; mf < 4; ++mf)
#pragma unroll
        for (int nf = 0; nf < 4; ++nf)
          acc[mf][nf] = __builtin_amdgcn_mfma_f32_16x16x32_f16(af[mf], bfr[nf],
                                                               acc[mf][nf], 0, 0, 0);
    }
    __syncthreads();
  }
#pragma unroll
  for (int nf = 0; nf < 4; ++nf) {
    int col = wn * 64 + nf * 16 + ln15;
    float bo = bout[col];
#pragma unroll
    for (int mf = 0; mf < 4; ++mf) {
      int rbase = wm * 64 + mf * 16 + quad * 4;
#pragma unroll
      for (int v = 0; v < 4; ++v)
        outb[(size_t)(tok0 + rbase + v) * 128 + col] = acc[mf][nf][v] + bo;
    }
  }
}

extern "C" void kernel_launch(void* const* d_in, const int* in_sizes, int n_in,
                              void* d_out, int out_size, void* d_ws, size_t ws_size,
                              hipStream_t stream) {
  const float* x    = (const float*)d_in[0];
  const float* Wfx  = (const float*)d_in[1];
  const float* bfx  = (const float*)d_in[2];
  const float* Wx   = (const float*)d_in[3];
  const float* bx   = (const float*)d_in[4];
  const float* Wsl  = (const float*)d_in[5];
  const float* bsl  = (const float*)d_in[6];
  const float* temp = (const float*)d_in[7];
  const float* Wq   = (const float*)d_in[8];
  const float* Wk   = (const float*)d_in[9];
  const float* Wv   = (const float*)d_in[10];
  const float* Wout = (const float*)d_in[11];
  const float* bout = (const float*)d_in[12];
  float* out = (float*)d_out;
  char* ws = (char*)d_ws;

  f16*  padx = (f16*)(ws + OFF_PADX);
  float* STp = (float*)(ws + OFF_STP);   // aliases padx (dead after conv)
  float* snp = (float*)(ws + OFF_SNP);   // aliases padx
  f16*  wcat = (f16*)(ws + OFF_WCAT);
  f16*  PT   = (f16*)(ws + OFF_PT);
  f16*  xmid = (f16*)(ws + OFF_XMID);
  f16*  fxT  = (f16*)(ws + OFF_FXT);

  prepw_kernel<<<4608, 256, 0, stream>>>(Wfx, Wx, wcat);
  for (int b = 0; b < 2; ++b) {
    const float* xb = x + (size_t)b * 65536 * 128;
    float* outb = out + (size_t)b * 65536 * 128;
    pad_kernel<<<4161, 256, 0, stream>>>(xb, padx);
    conv_kernel<<<4096, 256, 0, stream>>>(padx, wcat, bfx, bx, xmid, fxT);
    slice_kernel<<<512, 256, 0, stream>>>(xmid, fxT, Wsl, bsl, temp, STp, snp);
    attn_pt_kernel<<<8, 256, 0, stream>>>(STp, snp, Wq, Wk, Wv, Wout, PT);
    final_kernel<<<512, 256, 0, stream>>>(xmid, PT, bout, outb);
  }
}

// Round 9
// 845.510 us; speedup vs baseline: 1.0763x; 1.0763x over previous
//
#include <hip/hip_runtime.h>

// R14: fix R13's regression. R13 post-mortem: slice de-scatter/de-atomic saved
//  ~120 us/dispatch, BUT the 64-chunk ST reduction moved into 8-block attn_pt
//  ran at 0.37% occupancy -> 175 us (2048 threads pulling 8.4 MB at 27 GB/s,
//  no latency hiding). Keep R13 slice; add a 130-block reduce_kernel (1 thread
//  per output element, 64-deep sum, coalesced 256B/wave reads, L2-hot) writing
//  reduced ST[8][4096]+snorm[8][64] into the free workspace slot; attn_pt
//  reverts to its cheap R12 read pattern.
// Per-batch workspace (total 154,012,672 B):
//   padx  f16 [258][258][128]  @ 0           (17,040,384)
//     STp   f32 [512][4096]    @ 0           ( 8,388,608)  aliases padx
//     snormp f32 [512][64]     @ 8,388,608   (   131,072)  aliases padx
//   wcat  f16 [9][1024][128]   @ 17,040,384  ( 2,359,296)
//   ST    f32 [8][4096]        @ 19,399,680  (   131,072)  reduced
//   norm  f32 [8][64]          @ 19,530,752  (     2,048)  reduced
//   PT    f16 [128][512]       @ 19,663,872  (   131,072)
//   xmid  f16 [65536][512]     @ 19,794,944  (67,108,864)
//   fxT   f16 [512][65536]     @ 86,903,808  (67,108,864)

typedef _Float16 f16;
typedef _Float16 f16x8 __attribute__((ext_vector_type(8)));
typedef _Float16 f16x4 __attribute__((ext_vector_type(4)));
typedef float    f32x4 __attribute__((ext_vector_type(4)));

static const size_t OFF_PADX = 0;
static const size_t OFF_STP  = 0;            // aliases padx (dead after conv)
static const size_t OFF_SNP  = 8388608;      // aliases padx
static const size_t OFF_WCAT = 17040384;
static const size_t OFF_ST   = 19399680;
static const size_t OFF_NORM = 19530752;
static const size_t OFF_PT   = 19663872;
static const size_t OFF_XMID = 19794944;
static const size_t OFF_FXT  = 86903808;

__device__ __forceinline__ void ldsdma16(f16* lds, const f16* g) {
  __builtin_amdgcn_global_load_lds((__attribute__((address_space(1))) void*)g,
                                   (__attribute__((address_space(3))) void*)lds,
                                   16, 0, 0);
}

// ---------------------------------------------------------------- pad + cast x
__global__ __launch_bounds__(256) void pad_kernel(const float* __restrict__ xb,
                                                  f16* __restrict__ padx) {
  int idx = blockIdx.x * 256 + threadIdx.x;           // over [258][258][16]
  if (idx >= 258 * 258 * 16) return;
  int c8 = (idx & 15) * 8;
  int r  = idx >> 4;                                  // ip*258 + jp
  int jp = r % 258;
  int ip = r / 258;
  f16x8 v;
  if (ip == 0 || ip == 257 || jp == 0 || jp == 257) {
#pragma unroll
    for (int j = 0; j < 8; ++j) v[j] = (f16)0.0f;
  } else {
    const float* src = xb + ((size_t)(ip - 1) * 256 + (jp - 1)) * 128 + c8;
#pragma unroll
    for (int j = 0; j < 8; ++j) v[j] = (f16)src[j];
  }
  *(f16x8*)(padx + (size_t)r * 128 + c8) = v;
}

// ------------------------------------------- weights: Wcat_T[tap][co(1024)][ci]
__global__ __launch_bounds__(256) void prepw_kernel(const float* __restrict__ Wfx,
                                                    const float* __restrict__ Wx,
                                                    f16* __restrict__ wcat) {
  int idx = blockIdx.x * 256 + threadIdx.x;           // (tap*1024+co)*128+ci
  if (idx >= 9 * 1024 * 128) return;
  int ci = idx & 127;
  int t  = idx >> 7;
  int co = t & 1023;
  int tap = t >> 10;
  float v = (co < 512) ? Wfx[(size_t)(tap * 128 + ci) * 512 + co]
                       : Wx[(size_t)(tap * 128 + ci) * 512 + (co - 512)];
  wcat[idx] = (f16)v;
}

// --------------------------------------------------- fused conv: implicit GEMM
// 18-phase pipeline on R9 geometry + XCD-chunked block swizzle (R11).
__global__ __launch_bounds__(256, 2) void conv_kernel(const f16* __restrict__ padx,
                                                      const f16* __restrict__ wcat,
                                                      const float* __restrict__ bfx,
                                                      const float* __restrict__ bx,
                                                      f16* __restrict__ xmid,
                                                      f16* __restrict__ fxT) {
  __shared__ f16 smem[33024];        // 66,048 B total
  f16* As0 = smem;                   // [130][64] swizzled: slot rr*64 + (c^(rr&7))*8
  f16* As1 = smem + 8320;
  f16* Bs0 = smem + 16640;           // [128][64] same swizzle
  f16* Bs1 = smem + 24832;
  int tid = threadIdx.x;
  // XCD-chunked swizzle (bijective: 4096 % 8 == 0)
  int wg = (blockIdx.x & 7) * 512 + (blockIdx.x >> 3);
  int nt = wg & 7;
  int mt = wg >> 3;                  // 0..511
  int i  = mt >> 1;
  int j0 = (mt & 1) * 128;
  int n0 = nt * 128;
  int lane = tid & 63, wave = tid >> 6;
  int ln15 = lane & 15, quad = lane >> 4;
  int wm = wave & 1, wn = wave >> 1;

  f32x4 acc[4][4] = {};

  auto stageA = [&](int di, int kc, f16* dst) {   // 130 rows x 8 chunks = 1040 slots
#pragma unroll
    for (int ph = 0; ph < 5; ++ph) {
      int s = ph * 256 + tid;
      if (ph < 4 || s < 1040) {
        int rr = s >> 3;
        int qq = ((s & 7) ^ (rr & 7)) * 8;
        ldsdma16(&dst[(ph * 256 + wave * 64) * 8],
                 padx + ((size_t)(i + di) * 258 + j0 + rr) * 128 + kc + qq);
      }
    }
  };
  auto stageB = [&](int tap, int kc, f16* dst) {  // 128 rows x 8 chunks = 1024 slots
#pragma unroll
    for (int ph = 0; ph < 4; ++ph) {
      int s = ph * 256 + tid;
      int rr = s >> 3;
      int qq = ((s & 7) ^ (rr & 7)) * 8;
      ldsdma16(&dst[(ph * 256 + wave * 64) * 8],
               wcat + ((size_t)(tap * 1024 + n0 + rr)) * 128 + kc + qq);
    }
  };
  auto computePhase = [&](int dj, const f16* A, const f16* B) {
#pragma unroll
    for (int ks = 0; ks < 2; ++ks) {
      int q = ks * 4 + quad;         // 0..7 k-chunk within plane
      f16x8 af[4], bfr[4];
#pragma unroll
      for (int xx = 0; xx < 4; ++xx) {
        int t  = dj + wm * 64 + xx * 16 + ln15;
        int rb = wn * 64 + xx * 16 + ln15;
        af[xx]  = *(const f16x8*)(&A[t * 64 + ((q ^ (t & 7)) * 8)]);
        bfr[xx] = *(const f16x8*)(&B[rb * 64 + ((q ^ (rb & 7)) * 8)]);
      }
      __builtin_amdgcn_s_setprio(1);
#pragma unroll
      for (int mf = 0; mf < 4; ++mf)
#pragma unroll
        for (int nf = 0; nf < 4; ++nf)
          acc[mf][nf] = __builtin_amdgcn_mfma_f32_16x16x32_f16(af[mf], bfr[nf],
                                                               acc[mf][nf], 0, 0, 0);
      __builtin_amdgcn_s_setprio(0);
    }
  };

  // ---- prologue: first A plane + first B plane
  stageA(0, 0, As0);
  stageB(0, 0, Bs0);
  __syncthreads();

  // ---- 18 phases: p = di*6 + kc2*3 + dj (all decode constant under unroll)
#pragma unroll
  for (int p = 0; p < 18; ++p) {
    int dj   = p % 3;
    int dikc = p / 3;
    if (p + 1 < 18) {
      int np = p + 1;
      int ndj = np % 3, ndikc = np / 3;
      int ndi = ndikc >> 1, nkc = (ndikc & 1) * 64;
      stageB(ndi * 3 + ndj, nkc, (np & 1) ? Bs1 : Bs0);
      if (ndj == 0) stageA(ndi, nkc, (ndikc & 1) ? As1 : As0);
    }
    computePhase(dj, (dikc & 1) ? As1 : As0, (p & 1) ? Bs1 : Bs0);
    __syncthreads();
  }

  size_t token0 = (size_t)i * 256 + j0;
  if (nt < 4) {
    // ---- fxT path: bias, transpose through LDS, f16x8 coalesced stores
    f16* tile = smem;                // [col 128][token 128] stride 136 (34,816 B)
#pragma unroll
    for (int nf = 0; nf < 4; ++nf) {
      int colLoc = wn * 64 + nf * 16 + ln15;
      float bias = bfx[n0 + colLoc];
#pragma unroll
      for (int mf = 0; mf < 4; ++mf) {
        int tokBase = wm * 64 + mf * 16 + quad * 4;
        f16x4 pk;
#pragma unroll
        for (int v = 0; v < 4; ++v) pk[v] = (f16)(acc[mf][nf][v] + bias);
        *(f16x4*)(&tile[colLoc * 136 + tokBase]) = pk;
      }
    }
    __syncthreads();
#pragma unroll
    for (int it2 = 0; it2 < 8; ++it2) {
      int s = it2 * 256 + tid;       // 0..2047
      int c = s >> 4, t8 = s & 15;
      f16x8 vv = *(const f16x8*)(&tile[c * 136 + t8 * 8]);
      *(f16x8*)(fxT + (size_t)(n0 + c) * 65536 + token0 + t8 * 8) = vv;
    }
  } else {
    // ---- xmid path: token-major rows
#pragma unroll
    for (int nf = 0; nf < 4; ++nf) {
      int col = n0 + wn * 64 + nf * 16 + ln15;
      float bias = bx[col - 512];
#pragma unroll
      for (int mf = 0; mf < 4; ++mf) {
        int rbase = wm * 64 + mf * 16 + quad * 4;
#pragma unroll
        for (int v = 0; v < 4; ++v)
          xmid[(size_t)(token0 + rbase + v) * 512 + (col - 512)] =
              (f16)(acc[mf][nf][v] + bias);
      }
    }
  }
}

// ---------------- slice: MFMA logits -> shfl softmax -> W overlay + MFMA ST acc
// R13: overlay writes LDS-staged + coalesced f16x8; ST/norm partials non-atomic.
#define WS_S 72
#define WT_S 264
__global__ __launch_bounds__(256, 2) void slice_kernel(f16* __restrict__ xmid,
                                                       const f16* __restrict__ fxT,
                                                       const float* __restrict__ Wslice,
                                                       const float* __restrict__ bslice,
                                                       const float* __restrict__ temperature,
                                                       float* __restrict__ STp,
                                                       float* __restrict__ snormp) {
  __shared__ f16 Ws[64 * WS_S];      // [g][d] f16, padded
  __shared__ f16 Wt[64 * WT_S];      // [g][t_local 256] padded, wave-private t-stripes
  __shared__ float red[64 * 65];     // cross-wave ST reduction
  __shared__ float redn[64];
  __shared__ __align__(16) f16 wtile[4 * 16 * 72];  // per-wave [16 tok][72] overlay tile
  int tid = threadIdx.x;
  int h = blockIdx.x >> 6;           // 8
  int chunk = blockIdx.x & 63;       // 64 chunks of 1024 tokens
  int tok0 = chunk * 1024;
  int lane = tid & 63, wave = tid >> 6;
  int ln15 = lane & 15, quad = lane >> 4;
  f16* wt = wtile + wave * (16 * 72);

  for (int s = tid; s < 4096; s += 256)
    Ws[(s >> 6) * WS_S + (s & 63)] = (f16)Wslice[s];
  if (tid < 64) redn[tid] = 0.f;
  float tc = temperature[h];
  tc = fminf(fmaxf(tc, 0.1f), 5.0f);
  float invt = 1.0f / tc;
  float bsv[4];
#pragma unroll
  for (int nf = 0; nf < 4; ++nf) bsv[nf] = bslice[nf * 16 + ln15];
  __syncthreads();

  f32x4 acc2[4][4] = {};             // ST partial: [mf->g][nf->d]
  float naccv[4] = {};               // norm partial per nf (g = nf*16+ln15)

  for (int it = 0; it < 4; ++it) {
    int tsub = it * 256 + wave * 64;            // this wave's 64 tokens (local)
    // ---- phase A: logits via MFMA (A direct from global, B from LDS Ws)
    f32x4 accA[4][4] = {};
#pragma unroll
    for (int kq = 0; kq < 2; ++kq) {
      f16x8 bf[4];
#pragma unroll
      for (int nf = 0; nf < 4; ++nf)
        bf[nf] = *(const f16x8*)(&Ws[(nf * 16 + ln15) * WS_S + kq * 32 + quad * 8]);
#pragma unroll
      for (int mf = 0; mf < 4; ++mf) {
        f16x8 af = *(const f16x8*)(xmid + (size_t)(tok0 + tsub + mf * 16 + ln15) * 512 +
                                   h * 64 + kq * 32 + quad * 8);
#pragma unroll
        for (int nf = 0; nf < 4; ++nf)
          accA[mf][nf] = __builtin_amdgcn_mfma_f32_16x16x32_f16(af, bf[nf], accA[mf][nf],
                                                                0, 0, 0);
      }
    }
    // ---- softmax over g; stage overlay in wave-private LDS tile + Wt
#pragma unroll
    for (int mf = 0; mf < 4; ++mf) {
#pragma unroll
      for (int v = 0; v < 4; ++v) {
        float l[4];
#pragma unroll
        for (int nf = 0; nf < 4; ++nf) l[nf] = (accA[mf][nf][v] + bsv[nf]) * invt;
        float lm = fmaxf(fmaxf(l[0], l[1]), fmaxf(l[2], l[3]));
#pragma unroll
        for (int off = 1; off < 16; off <<= 1) lm = fmaxf(lm, __shfl_xor(lm, off, 64));
        float e[4], ssum = 0.f;
#pragma unroll
        for (int nf = 0; nf < 4; ++nf) { e[nf] = __expf(l[nf] - lm); ssum += e[nf]; }
#pragma unroll
        for (int off = 1; off < 16; off <<= 1) ssum += __shfl_xor(ssum, off, 64);
        float winv = 1.0f / ssum;
        int t_str = wave * 64 + mf * 16 + quad * 4 + v;  // local to 256-stripe set
#pragma unroll
        for (int nf = 0; nf < 4; ++nf) {
          float w = e[nf] * winv;
          naccv[nf] += w;
          f16 wh = (f16)w;
          wt[(quad * 4 + v) * 72 + nf * 16 + ln15] = wh;
          Wt[(nf * 16 + ln15) * WT_S + t_str] = wh;
        }
      }
      // coalesced overlay store: 16 token rows x 128 B (wave-private tile)
#pragma unroll
      for (int k = 0; k < 2; ++k) {
        int s = k * 64 + lane;
        int t8 = s >> 3, c8 = s & 7;
        f16x8 vv = *(const f16x8*)(&wt[t8 * 72 + c8 * 8]);
        *(f16x8*)(xmid + (size_t)(tok0 + tsub + mf * 16 + t8) * 512 + h * 64 + c8 * 8) = vv;
      }
    }
    // ---- phase B: acc2[g][d] += Wt^T-frag x fxT-frag (wave-private k-range)
#pragma unroll
    for (int kq = 0; kq < 2; ++kq) {
      int kof = wave * 64 + kq * 32 + quad * 8;          // within 256-stripe set
      f16x8 bfB[4];
#pragma unroll
      for (int nf = 0; nf < 4; ++nf)
        bfB[nf] = *(const f16x8*)(fxT + (size_t)(h * 64 + nf * 16 + ln15) * 65536 +
                                  tok0 + it * 256 + kof);
#pragma unroll
      for (int mf = 0; mf < 4; ++mf) {
        f16x8 afB = *(const f16x8*)(&Wt[(mf * 16 + ln15) * WT_S + kof]);
#pragma unroll
        for (int nf = 0; nf < 4; ++nf)
          acc2[mf][nf] = __builtin_amdgcn_mfma_f32_16x16x32_f16(afB, bfB[nf],
                                                                acc2[mf][nf], 0, 0, 0);
      }
    }
  }

  // ---- norm partials into LDS (16 contributors per g)
#pragma unroll
  for (int nf = 0; nf < 4; ++nf) atomicAdd(&redn[nf * 16 + ln15], naccv[nf]);

  // ---- cross-wave ST reduce, then non-atomic per-chunk partial writes
  for (int s = 0; s < 4; ++s) {
    if (wave == s) {
#pragma unroll
      for (int mf = 0; mf < 4; ++mf)
#pragma unroll
        for (int nf = 0; nf < 4; ++nf)
#pragma unroll
          for (int v = 0; v < 4; ++v) {
            int g = mf * 16 + quad * 4 + v;
            int d = nf * 16 + ln15;
            if (s == 0) red[g * 65 + d] = acc2[mf][nf][v];
            else        red[g * 65 + d] += acc2[mf][nf][v];
          }
    }
    __syncthreads();
  }
  float* stp = STp + ((size_t)h * 64 + chunk) * 4096;
  for (int s2 = tid; s2 < 4096; s2 += 256)
    stp[s2] = red[(s2 >> 6) * 65 + (s2 & 63)];
  if (tid < 64) snormp[((size_t)h * 64 + chunk) * 64 + tid] = redn[tid];
}

// --------- parallel 64-chunk reduction: STp[512][4096] -> ST[8][4096],
// --------- snormp[512][64] -> snorm[8][64]. 1 thread per output element.
__global__ __launch_bounds__(256) void reduce_kernel(const float* __restrict__ STp,
                                                     const float* __restrict__ snp,
                                                     float* __restrict__ ST,
                                                     float* __restrict__ snorm) {
  int idx = blockIdx.x * 256 + threadIdx.x;
  if (idx < 32768) {
    int h = idx >> 12, s = idx & 4095;
    const float* sp = STp + ((size_t)h * 64) * 4096 + s;
    float a = 0.f;
#pragma unroll 8
    for (int c = 0; c < 64; ++c) a += sp[(size_t)c * 4096];
    ST[idx] = a;
  } else if (idx < 33280) {
    int e = idx - 32768;
    int h = e >> 6, g = e & 63;
    const float* np = snp + ((size_t)h * 64) * 64 + g;
    float a = 0.f;
#pragma unroll 8
    for (int c = 0; c < 64; ++c) a += np[c * 64];
    snorm[e] = a;
  }
}

// --------- merged attn + PT fold (reads pre-reduced ST/snorm; R12 pattern)
__global__ __launch_bounds__(256) void attn_pt_kernel(const float* __restrict__ ST,
                                                      const float* __restrict__ snorm,
                                                      const float* __restrict__ Wq,
                                                      const float* __restrict__ Wk,
                                                      const float* __restrict__ Wv,
                                                      const float* __restrict__ Wout,
                                                      f16* __restrict__ PT) {
  int h = blockIdx.x;                // 8
  __shared__ float tok[64 * 65];     // aliased as scores later
  __shared__ float qs[64 * 65];
  __shared__ float ksm[64 * 65];     // aliased as out_slice later
  __shared__ f16 vsm[64 * 65];
  int tid = threadIdx.x;
  const float* stp = ST + (size_t)h * 4096;
  const float* snp = snorm + (size_t)h * 64;
  for (int s = tid; s < 4096; s += 256) {
    int g = s >> 6, d = s & 63;
    tok[g * 65 + d] = stp[s] / (snp[g] + 1e-5f);
  }
  __syncthreads();
  int g = tid >> 2, p16 = (tid & 3) * 16;
  for (int e0 = 0; e0 < 16; ++e0) {
    int e = p16 + e0;
    const float* wq = Wq + e * 64;
    const float* wk = Wk + e * 64;
    const float* wv = Wv + e * 64;
    float aq = 0, ak = 0, av = 0;
#pragma unroll 8
    for (int d = 0; d < 64; ++d) {
      float tv = tok[g * 65 + d];
      aq += tv * wq[d];
      ak += tv * wk[d];
      av += tv * wv[d];
    }
    qs[g * 65 + e] = aq;
    ksm[g * 65 + e] = ak;
    vsm[g * 65 + e] = (f16)av;
  }
  __syncthreads();
  float* sc = tok;  // alias, tok dead
  for (int f0 = 0; f0 < 16; ++f0) {
    int f = p16 + f0;
    float s = 0;
#pragma unroll 8
    for (int e = 0; e < 64; ++e) s += qs[g * 65 + e] * ksm[f * 65 + e];
    sc[g * 65 + f] = s * 0.125f;
  }
  __syncthreads();
  if (tid < 64) {
    float m = -1e30f;
    for (int f = 0; f < 64; ++f) m = fmaxf(m, sc[tid * 65 + f]);
    float ssum = 0;
    for (int f = 0; f < 64; ++f) {
      float e = __expf(sc[tid * 65 + f] - m);
      sc[tid * 65 + f] = e;
      ssum += e;
    }
    float inv = 1.0f / ssum;
    for (int f = 0; f < 64; ++f) sc[tid * 65 + f] *= inv;
  }
  __syncthreads();
  // out_slice -> os LDS (overwrite ksm; dead after scores)
  float* os = ksm;
  for (int e0 = 0; e0 < 16; ++e0) {
    int e = p16 + e0;
    float o = 0;
#pragma unroll 8
    for (int f = 0; f < 64; ++f) o += sc[g * 65 + f] * (float)vsm[f * 65 + e];
    os[g * 65 + e] = o;
  }
  __syncthreads();
  // ---- PT fold (os from LDS)
  int o = tid >> 1, gh = (tid & 1) * 32;
  const float* wr = Wout + (size_t)o * 512 + h * 64;
  float wreg[64];
#pragma unroll
  for (int d = 0; d < 64; ++d) wreg[d] = wr[d];
  for (int gg = 0; gg < 32; ++gg) {
    int gI = gh + gg;
    float s = 0;
#pragma unroll
    for (int d = 0; d < 64; ++d) s += os[gI * 65 + d] * wreg[d];
    PT[(size_t)o * 512 + h * 64 + gI] = (f16)s;
  }
}

// -------------------- final: out[n,o] = sum_k W[n,k] * PT[o,k] + bout[o]
// R5 structure (32 KB LDS -> 5 blocks/CU; occupancy > pipelining for streaming).
__global__ __launch_bounds__(256, 2) void final_kernel(const f16* __restrict__ xmid,
                                                       const f16* __restrict__ PT,
                                                       const float* __restrict__ bout,
                                                       float* __restrict__ outb) {
  __shared__ f16 As[128 * 64];
  __shared__ f16 Bs[128 * 64];
  int tid = threadIdx.x;
  int tok0 = blockIdx.x << 7;        // 512 blocks
  int lane = tid & 63, wave = tid >> 6;
  int ln15 = lane & 15, quad = lane >> 4;
  int wm = wave & 1, wn = wave >> 1;
  int rr[4], qq8[4];
#pragma unroll
  for (int ph = 0; ph < 4; ++ph) {
    int s = ph * 256 + tid;
    rr[ph] = s >> 3;
    qq8[ph] = ((s & 7) ^ (rr[ph] & 7)) * 8;
  }
  int wbase = wave * 512;
  f32x4 acc[4][4] = {};
  const f16* aB = xmid + (size_t)tok0 * 512;
  const f16* bB = PT;
  for (int kc = 0; kc < 512; kc += 64) {
#pragma unroll
    for (int ph = 0; ph < 4; ++ph) {
      ldsdma16(&As[ph * 2048 + wbase], aB + (size_t)rr[ph] * 512 + kc + qq8[ph]);
      ldsdma16(&Bs[ph * 2048 + wbase], bB + (size_t)rr[ph] * 512 + kc + qq8[ph]);
    }
    __syncthreads();
#pragma unroll
    for (int ks = 0; ks < 2; ++ks) {
      f16x8 af[4], bfr[4];
      int q = ks * 4 + quad;
#pragma unroll
      for (int xx = 0; xx < 4; ++xx) {
        int ra = wm * 64 + xx * 16 + ln15;
        int rb = wn * 64 + xx * 16 + ln15;
        af[xx]  = *(const f16x8*)(&As[ra * 64 + (q ^ (ra & 7)) * 8]);
        bfr[xx] = *(const f16x8*)(&Bs[rb * 64 + (q ^ (rb & 7)) * 8]);
      }
#pragma unroll
      for (int mf = 0; mf < 4; ++mf)
#pragma unroll
        for (int nf = 0; nf < 4; ++nf)
          acc[mf][nf] = __builtin_amdgcn_mfma_f32_16x16x32_f16(af[mf], bfr[nf],
                                                               acc[mf][nf], 0, 0, 0);
    }
    __syncthreads();
  }
#pragma unroll
  for (int nf = 0; nf < 4; ++nf) {
    int col = wn * 64 + nf * 16 + ln15;
    float bo = bout[col];
#pragma unroll
    for (int mf = 0; mf < 4; ++mf) {
      int rbase = wm * 64 + mf * 16 + quad * 4;
#pragma unroll
      for (int v = 0; v < 4; ++v)
        outb[(size_t)(tok0 + rbase + v) * 128 + col] = acc[mf][nf][v] + bo;
    }
  }
}

extern "C" void kernel_launch(void* const* d_in, const int* in_sizes, int n_in,
                              void* d_out, int out_size, void* d_ws, size_t ws_size,
                              hipStream_t stream) {
  const float* x    = (const float*)d_in[0];
  const float* Wfx  = (const float*)d_in[1];
  const float* bfx  = (const float*)d_in[2];
  const float* Wx   = (const float*)d_in[3];
  const float* bx   = (const float*)d_in[4];
  const float* Wsl  = (const float*)d_in[5];
  const float* bsl  = (const float*)d_in[6];
  const float* temp = (const float*)d_in[7];
  const float* Wq   = (const float*)d_in[8];
  const float* Wk   = (const float*)d_in[9];
  const float* Wv   = (const float*)d_in[10];
  const float* Wout = (const float*)d_in[11];
  const float* bout = (const float*)d_in[12];
  float* out = (float*)d_out;
  char* ws = (char*)d_ws;

  f16*  padx = (f16*)(ws + OFF_PADX);
  float* STp = (float*)(ws + OFF_STP);   // aliases padx (dead after conv)
  float* snp = (float*)(ws + OFF_SNP);   // aliases padx
  f16*  wcat = (f16*)(ws + OFF_WCAT);
  float* ST  = (float*)(ws + OFF_ST);
  float* nrm = (float*)(ws + OFF_NORM);
  f16*  PT   = (f16*)(ws + OFF_PT);
  f16*  xmid = (f16*)(ws + OFF_XMID);
  f16*  fxT  = (f16*)(ws + OFF_FXT);

  prepw_kernel<<<4608, 256, 0, stream>>>(Wfx, Wx, wcat);
  for (int b = 0; b < 2; ++b) {
    const float* xb = x + (size_t)b * 65536 * 128;
    float* outb = out + (size_t)b * 65536 * 128;
    pad_kernel<<<4161, 256, 0, stream>>>(xb, padx);
    conv_kernel<<<4096, 256, 0, stream>>>(padx, wcat, bfx, bx, xmid, fxT);
    slice_kernel<<<512, 256, 0, stream>>>(xmid, fxT, Wsl, bsl, temp, STp, snp);
    reduce_kernel<<<130, 256, 0, stream>>>(STp, snp, ST, nrm);
    attn_pt_kernel<<<8, 256, 0, stream>>>(ST, nrm, Wq, Wk, Wv, Wout, PT);
    final_kernel<<<512, 256, 0, stream>>>(xmid, PT, bout, outb);
  }
}

// Round 10
// 823.754 us; speedup vs baseline: 1.1047x; 1.0264x over previous
//
#include <hip/hip_runtime.h>

// R15: tail reverted to R12 exact (measured best, 829 us — the R13/R14
// partials+reduce arc netted negative vs R12's distributed atomics).
// conv rewritten with T4 counted-vmcnt pipelining:
//  - B tap-planes TRIPLE-buffered; A SINGLE-buffered [130][64] (padded to 1280
//    slots for uniform per-wave issue) + dj=2 fragments preloaded to registers
//    during the dj=1 phase so the A restage (issued at dj=2 entry) overlaps
//    that phase's MFMAs;
//  - phase barrier = s_waitcnt vmcnt(4) + raw s_barrier + sched_barrier(0) +
//    compiler fence: the just-issued B-stage (newest 4 loads) stays in flight
//    ACROSS the barrier (2 compute phases of flight); vmcnt(0) only at p16.
//    (R12's __syncthreads drained everything each phase = the ~24% stall.)
//  - LDS 68 KB -> still 2 blocks/CU; same stride-64 bank-clean swizzles.
// Per-batch workspace (total 154,012,672 B):
//   padx  f16 [258][258][128]  @ 0           (17,040,384)
//   wcat  f16 [9][1024][128]   @ 17,040,384  ( 2,359,296)
//   ST    f32 [8][64][64]      @ 19,399,680  (   131,072)  memset 0 per batch
//   norm  f32 [8][64]          @ 19,530,752  (     2,048)  memset 0 per batch
//   PT    f16 [128][512]       @ 19,663,872  (   131,072)
//   xmid  f16 [65536][512]     @ 19,794,944  (67,108,864)
//   fxT   f16 [512][65536]     @ 86,903,808  (67,108,864)

typedef _Float16 f16;
typedef _Float16 f16x8 __attribute__((ext_vector_type(8)));
typedef _Float16 f16x4 __attribute__((ext_vector_type(4)));
typedef float    f32x4 __attribute__((ext_vector_type(4)));

static const size_t OFF_PADX = 0;
static const size_t OFF_WCAT = 17040384;
static const size_t OFF_ST   = 19399680;
static const size_t OFF_NORM = 19530752;
static const size_t OFF_PT   = 19663872;
static const size_t OFF_XMID = 19794944;
static const size_t OFF_FXT  = 86903808;

__device__ __forceinline__ void ldsdma16(f16* lds, const f16* g) {
  __builtin_amdgcn_global_load_lds((__attribute__((address_space(1))) void*)g,
                                   (__attribute__((address_space(3))) void*)lds,
                                   16, 0, 0);
}

template <int N>
__device__ __forceinline__ void vmwait() {
  asm volatile("s_waitcnt vmcnt(%0)" ::"n"(N) : "memory");
}
__device__ __forceinline__ void phase_barrier() {
  __builtin_amdgcn_s_barrier();
  __builtin_amdgcn_sched_barrier(0);
  asm volatile("" ::: "memory");
}

// ---------------------------------------------------------------- pad + cast x
__global__ __launch_bounds__(256) void pad_kernel(const float* __restrict__ xb,
                                                  f16* __restrict__ padx) {
  int idx = blockIdx.x * 256 + threadIdx.x;           // over [258][258][16]
  if (idx >= 258 * 258 * 16) return;
  int c8 = (idx & 15) * 8;
  int r  = idx >> 4;                                  // ip*258 + jp
  int jp = r % 258;
  int ip = r / 258;
  f16x8 v;
  if (ip == 0 || ip == 257 || jp == 0 || jp == 257) {
#pragma unroll
    for (int j = 0; j < 8; ++j) v[j] = (f16)0.0f;
  } else {
    const float* src = xb + ((size_t)(ip - 1) * 256 + (jp - 1)) * 128 + c8;
#pragma unroll
    for (int j = 0; j < 8; ++j) v[j] = (f16)src[j];
  }
  *(f16x8*)(padx + (size_t)r * 128 + c8) = v;
}

// ------------------------------------------- weights: Wcat_T[tap][co(1024)][ci]
__global__ __launch_bounds__(256) void prepw_kernel(const float* __restrict__ Wfx,
                                                    const float* __restrict__ Wx,
                                                    f16* __restrict__ wcat) {
  int idx = blockIdx.x * 256 + threadIdx.x;           // (tap*1024+co)*128+ci
  if (idx >= 9 * 1024 * 128) return;
  int ci = idx & 127;
  int t  = idx >> 7;
  int co = t & 1023;
  int tap = t >> 10;
  float v = (co < 512) ? Wfx[(size_t)(tap * 128 + ci) * 512 + co]
                       : Wx[(size_t)(tap * 128 + ci) * 512 + (co - 512)];
  wcat[idx] = (f16)v;
}

// --------------------------------------------------- fused conv: implicit GEMM
// Counted-vmcnt 18-phase pipeline: A single + reg-preload, B triple-buffered.
__global__ __launch_bounds__(256, 2) void conv_kernel(const f16* __restrict__ padx,
                                                      const f16* __restrict__ wcat,
                                                      const float* __restrict__ bfx,
                                                      const float* __restrict__ bx,
                                                      f16* __restrict__ xmid,
                                                      f16* __restrict__ fxT) {
  __shared__ f16 smem[34816];        // 69,632 B: A 20,480 + 3 x B 16,384
  f16* As  = smem;                   // [1280 slots x 16B]; rows 0..129 real
  f16* Bs0 = smem + 10240;           // [128][64] swizzled, stride 64
  f16* Bs1 = smem + 18432;
  f16* Bs2 = smem + 26624;
  int tid = threadIdx.x;
  // XCD-chunked swizzle (bijective: 4096 % 8 == 0)
  int wg = (blockIdx.x & 7) * 512 + (blockIdx.x >> 3);
  int nt = wg & 7;
  int mt = wg >> 3;                  // 0..511
  int i  = mt >> 1;
  int j0 = (mt & 1) * 128;
  int n0 = nt * 128;
  int lane = tid & 63, wave = tid >> 6;
  int ln15 = lane & 15, quad = lane >> 4;
  int wm = wave & 1, wn = wave >> 1;

  f32x4 acc[4][4] = {};

  // uniform-issue A stage: 5 gload_lds per thread per call; slots >=1040 are
  // pad (junk), read address clamped to stay in padx row.
  auto stageA = [&](int di, int kc) {
#pragma unroll
    for (int ph = 0; ph < 5; ++ph) {
      int s = ph * 256 + tid;
      int rr = s >> 3;
      int rrc = rr < 130 ? rr : 129;
      int qq = ((s & 7) ^ (rr & 7)) * 8;
      ldsdma16(&As[(ph * 256 + wave * 64) * 8],
               padx + ((size_t)(i + di) * 258 + j0 + rrc) * 128 + kc + qq);
    }
  };
  auto stageB = [&](int tap, int kc, f16* dst) {  // 4 gload_lds per thread
#pragma unroll
    for (int ph = 0; ph < 4; ++ph) {
      int s = ph * 256 + tid;
      int rr = s >> 3;
      int qq = ((s & 7) ^ (rr & 7)) * 8;
      ldsdma16(&dst[(ph * 256 + wave * 64) * 8],
               wcat + ((size_t)(tap * 1024 + n0 + rr)) * 128 + kc + qq);
    }
  };
  auto computeA = [&](int dj, const f16* B) {     // dj = 0 or 1, A from LDS
#pragma unroll
    for (int ks = 0; ks < 2; ++ks) {
      int q = ks * 4 + quad;
      f16x8 af[4], bfr[4];
#pragma unroll
      for (int xx = 0; xx < 4; ++xx) {
        int t  = dj + wm * 64 + xx * 16 + ln15;
        int rb = wn * 64 + xx * 16 + ln15;
        af[xx]  = *(const f16x8*)(&As[t * 64 + ((q ^ (t & 7)) * 8)]);
        bfr[xx] = *(const f16x8*)(&B[rb * 64 + ((q ^ (rb & 7)) * 8)]);
      }
      __builtin_amdgcn_s_setprio(1);
#pragma unroll
      for (int mf = 0; mf < 4; ++mf)
#pragma unroll
        for (int nf = 0; nf < 4; ++nf)
          acc[mf][nf] = __builtin_amdgcn_mfma_f32_16x16x32_f16(af[mf], bfr[nf],
                                                               acc[mf][nf], 0, 0, 0);
      __builtin_amdgcn_s_setprio(0);
    }
  };

  f16x8 afr[2][4];                   // dj=2 A fragments (preloaded at dj=1)
  auto preloadAfr = [&]() {
#pragma unroll
    for (int ks = 0; ks < 2; ++ks) {
      int q = ks * 4 + quad;
#pragma unroll
      for (int xx = 0; xx < 4; ++xx) {
        int t = 2 + wm * 64 + xx * 16 + ln15;
        afr[ks][xx] = *(const f16x8*)(&As[t * 64 + ((q ^ (t & 7)) * 8)]);
      }
    }
  };
  auto computeR = [&](const f16* B) {             // dj = 2, A from registers
#pragma unroll
    for (int ks = 0; ks < 2; ++ks) {
      int q = ks * 4 + quad;
      f16x8 bfr[4];
#pragma unroll
      for (int xx = 0; xx < 4; ++xx) {
        int rb = wn * 64 + xx * 16 + ln15;
        bfr[xx] = *(const f16x8*)(&B[rb * 64 + ((q ^ (rb & 7)) * 8)]);
      }
      __builtin_amdgcn_s_setprio(1);
#pragma unroll
      for (int mf = 0; mf < 4; ++mf)
#pragma unroll
        for (int nf = 0; nf < 4; ++nf)
          acc[mf][nf] = __builtin_amdgcn_mfma_f32_16x16x32_f16(afr[ks][mf], bfr[nf],
                                                               acc[mf][nf], 0, 0, 0);
      __builtin_amdgcn_s_setprio(0);
    }
  };

  // ---- prologue: A(0) + B(0) + B(1); vmcnt(4) lets B(1) stay in flight.
  stageA(0, 0);                      // 5 loads
  stageB(0, 0, Bs0);                 // 4
  stageB(1, 0, Bs1);                 // 4
  vmwait<4>();
  phase_barrier();

  // ---- 18 phases; p compile-time under full unroll.
  // Issue order per phase: [A(d+1) if dj==2] then [B(p+2)]; barrier =
  // vmcnt(4) (p<16) / vmcnt(0) (p==16) + s_barrier. Oldest-first vmcnt
  // semantics guarantee B(p+1) (and A(d+1) at dj==2) landed.
#pragma unroll
  for (int p = 0; p < 18; ++p) {
    int dj = p % 3;
    int d  = p / 3;                  // dikc group: di = d>>1, kc = (d&1)*64
    if (dj == 2 && d < 5) {
      int dg = d + 1;
      stageA(dg >> 1, (dg & 1) * 64);
    }
    if (p + 2 < 18) {
      int np = p + 2;
      int ndikc = np / 3;
      int ntap = (ndikc >> 1) * 3 + (np % 3);
      int nkc  = (ndikc & 1) * 64;
      f16* dst = (np % 3 == 0) ? Bs0 : (np % 3 == 1) ? Bs1 : Bs2;
      stageB(ntap, nkc, dst);
    }
    const f16* Bp = (p % 3 == 0) ? Bs0 : (p % 3 == 1) ? Bs1 : Bs2;
    if (dj == 1) preloadAfr();       // A(d) dj=2 rows -> regs before restage
    if (dj < 2) computeA(dj, Bp);
    else        computeR(Bp);
    if (p < 16)      vmwait<4>();
    else if (p == 16) vmwait<0>();
    if (p < 17) phase_barrier();
  }

  size_t token0 = (size_t)i * 256 + j0;
  if (nt < 4) {
    // ---- fxT path: bias, transpose through LDS, f16x8 coalesced stores.
    // tile spans As+Bs0 (34,816 f16 needed? no — 17,408 f16 = 34,816 B);
    // compute(17) reads only Bs2 — disjoint, no barrier needed before writes.
    f16* tile = smem;                // [col 128][token 128] stride 136
#pragma unroll
    for (int nf = 0; nf < 4; ++nf) {
      int colLoc = wn * 64 + nf * 16 + ln15;
      float bias = bfx[n0 + colLoc];
#pragma unroll
      for (int mf = 0; mf < 4; ++mf) {
        int tokBase = wm * 64 + mf * 16 + quad * 4;
        f16x4 pk;
#pragma unroll
        for (int v = 0; v < 4; ++v) pk[v] = (f16)(acc[mf][nf][v] + bias);
        *(f16x4*)(&tile[colLoc * 136 + tokBase]) = pk;
      }
    }
    __syncthreads();
#pragma unroll
    for (int it2 = 0; it2 < 8; ++it2) {
      int s = it2 * 256 + tid;       // 0..2047
      int c = s >> 4, t8 = s & 15;
      f16x8 vv = *(const f16x8*)(&tile[c * 136 + t8 * 8]);
      *(f16x8*)(fxT + (size_t)(n0 + c) * 65536 + token0 + t8 * 8) = vv;
    }
  } else {
    // ---- xmid path: token-major rows
#pragma unroll
    for (int nf = 0; nf < 4; ++nf) {
      int col = n0 + wn * 64 + nf * 16 + ln15;
      float bias = bx[col - 512];
#pragma unroll
      for (int mf = 0; mf < 4; ++mf) {
        int rbase = wm * 64 + mf * 16 + quad * 4;
#pragma unroll
        for (int v = 0; v < 4; ++v)
          xmid[(size_t)(token0 + rbase + v) * 512 + (col - 512)] =
              (f16)(acc[mf][nf][v] + bias);
      }
    }
  }
}

// ---------------- slice: MFMA logits -> shfl softmax -> W overlay + MFMA ST acc
#define WS_S 72
#define WT_S 264
__global__ __launch_bounds__(256, 2) void slice_kernel(f16* __restrict__ xmid,
                                                       const f16* __restrict__ fxT,
                                                       const float* __restrict__ Wslice,
                                                       const float* __restrict__ bslice,
                                                       const float* __restrict__ temperature,
                                                       float* __restrict__ ST,
                                                       float* __restrict__ snorm) {
  __shared__ f16 Ws[64 * WS_S];      // [g][d] f16, padded
  __shared__ f16 Wt[64 * WT_S];      // [g][t_local 256] padded, wave-private t-stripes
  __shared__ float red[64 * 65];     // cross-wave ST reduction
  __shared__ float redn[64];
  int tid = threadIdx.x;
  int h = blockIdx.x >> 6;           // 8
  int chunk = blockIdx.x & 63;       // 64 chunks of 1024 tokens
  int tok0 = chunk * 1024;
  int lane = tid & 63, wave = tid >> 6;
  int ln15 = lane & 15, quad = lane >> 4;

  for (int s = tid; s < 4096; s += 256)
    Ws[(s >> 6) * WS_S + (s & 63)] = (f16)Wslice[s];
  if (tid < 64) redn[tid] = 0.f;
  float tc = temperature[h];
  tc = fminf(fmaxf(tc, 0.1f), 5.0f);
  float invt = 1.0f / tc;
  float bsv[4];
#pragma unroll
  for (int nf = 0; nf < 4; ++nf) bsv[nf] = bslice[nf * 16 + ln15];
  __syncthreads();

  f32x4 acc2[4][4] = {};             // ST partial: [mf->g][nf->d]
  float naccv[4] = {};               // norm partial per nf (g = nf*16+ln15)

  for (int it = 0; it < 4; ++it) {
    int tsub = it * 256 + wave * 64;            // this wave's 64 tokens (local)
    // ---- phase A: logits via MFMA (A direct from global, B from LDS Ws)
    f32x4 accA[4][4] = {};
#pragma unroll
    for (int kq = 0; kq < 2; ++kq) {
      f16x8 bf[4];
#pragma unroll
      for (int nf = 0; nf < 4; ++nf)
        bf[nf] = *(const f16x8*)(&Ws[(nf * 16 + ln15) * WS_S + kq * 32 + quad * 8]);
#pragma unroll
      for (int mf = 0; mf < 4; ++mf) {
        f16x8 af = *(const f16x8*)(xmid + (size_t)(tok0 + tsub + mf * 16 + ln15) * 512 +
                                   h * 64 + kq * 32 + quad * 8);
#pragma unroll
        for (int nf = 0; nf < 4; ++nf)
          accA[mf][nf] = __builtin_amdgcn_mfma_f32_16x16x32_f16(af, bf[nf], accA[mf][nf],
                                                                0, 0, 0);
      }
    }
    // ---- softmax over g (4 in-lane nf x 16 lanes), write W overlay + Wt
#pragma unroll
    for (int mf = 0; mf < 4; ++mf) {
#pragma unroll
      for (int v = 0; v < 4; ++v) {
        float l[4];
#pragma unroll
        for (int nf = 0; nf < 4; ++nf) l[nf] = (accA[mf][nf][v] + bsv[nf]) * invt;
        float lm = fmaxf(fmaxf(l[0], l[1]), fmaxf(l[2], l[3]));
#pragma unroll
        for (int off = 1; off < 16; off <<= 1) lm = fmaxf(lm, __shfl_xor(lm, off, 64));
        float e[4], ssum = 0.f;
#pragma unroll
        for (int nf = 0; nf < 4; ++nf) { e[nf] = __expf(l[nf] - lm); ssum += e[nf]; }
#pragma unroll
        for (int off = 1; off < 16; off <<= 1) ssum += __shfl_xor(ssum, off, 64);
        float winv = 1.0f / ssum;
        int t_loc = tsub + mf * 16 + quad * 4 + v;       // local to 1024-chunk
        int t_str = wave * 64 + mf * 16 + quad * 4 + v;  // local to 256-stripe set
        f16* wrow = xmid + (size_t)(tok0 + t_loc) * 512 + h * 64;
#pragma unroll
        for (int nf = 0; nf < 4; ++nf) {
          float w = e[nf] * winv;
          naccv[nf] += w;
          f16 wh = (f16)w;
          wrow[nf * 16 + ln15] = wh;
          Wt[(nf * 16 + ln15) * WT_S + t_str] = wh;
        }
      }
    }
    // ---- phase B: acc2[g][d] += Wt^T-frag x fxT-frag (wave-private k-range)
#pragma unroll
    for (int kq = 0; kq < 2; ++kq) {
      int kof = wave * 64 + kq * 32 + quad * 8;          // within 256-stripe set
      f16x8 bfB[4];
#pragma unroll
      for (int nf = 0; nf < 4; ++nf)
        bfB[nf] = *(const f16x8*)(fxT + (size_t)(h * 64 + nf * 16 + ln15) * 65536 +
                                  tok0 + it * 256 + kof);
#pragma unroll
      for (int mf = 0; mf < 4; ++mf) {
        f16x8 afB = *(const f16x8*)(&Wt[(mf * 16 + ln15) * WT_S + kof]);
#pragma unroll
        for (int nf = 0; nf < 4; ++nf)
          acc2[mf][nf] = __builtin_amdgcn_mfma_f32_16x16x32_f16(afB, bfB[nf],
                                                                acc2[mf][nf], 0, 0, 0);
      }
    }
  }

  // ---- norm partials into LDS (16 contributors per g)
#pragma unroll
  for (int nf = 0; nf < 4; ++nf) atomicAdd(&redn[nf * 16 + ln15], naccv[nf]);

  // ---- cross-wave ST reduce + global atomics
  for (int s = 0; s < 4; ++s) {
    if (wave == s) {
#pragma unroll
      for (int mf = 0; mf < 4; ++mf)
#pragma unroll
        for (int nf = 0; nf < 4; ++nf)
#pragma unroll
          for (int v = 0; v < 4; ++v) {
            int g = mf * 16 + quad * 4 + v;
            int d = nf * 16 + ln15;
            if (s == 0) red[g * 65 + d] = acc2[mf][nf][v];
            else        red[g * 65 + d] += acc2[mf][nf][v];
          }
    }
    __syncthreads();
  }
  float* stp = ST + (size_t)h * 4096;
  for (int s2 = tid; s2 < 4096; s2 += 256)
    atomicAdd(&stp[s2], red[(s2 >> 6) * 65 + (s2 & 63)]);
  if (tid < 64) atomicAdd(&snorm[h * 64 + tid], redn[tid]);
}

// --------- merged attn + PT fold: tiny attention, out_slice stays in LDS,
// --------- then PT[o][h*64+g] = sum_d out_slice[g][d] * Wout[o][h*64+d]
__global__ __launch_bounds__(256) void attn_pt_kernel(const float* __restrict__ ST,
                                                      const float* __restrict__ snorm,
                                                      const float* __restrict__ Wq,
                                                      const float* __restrict__ Wk,
                                                      const float* __restrict__ Wv,
                                                      const float* __restrict__ Wout,
                                                      f16* __restrict__ PT) {
  int h = blockIdx.x;                // 8
  __shared__ float tok[64 * 65];     // aliased as scores later
  __shared__ float qs[64 * 65];
  __shared__ float ksm[64 * 65];     // aliased as out_slice later
  __shared__ f16 vsm[64 * 65];
  int tid = threadIdx.x;
  const float* stp = ST + (size_t)h * 4096;
  const float* snp = snorm + (size_t)h * 64;
  for (int s = tid; s < 4096; s += 256) {
    int g = s >> 6, d = s & 63;
    tok[g * 65 + d] = stp[s] / (snp[g] + 1e-5f);
  }
  __syncthreads();
  int g = tid >> 2, p16 = (tid & 3) * 16;
  for (int e0 = 0; e0 < 16; ++e0) {
    int e = p16 + e0;
    const float* wq = Wq + e * 64;
    const float* wk = Wk + e * 64;
    const float* wv = Wv + e * 64;
    float aq = 0, ak = 0, av = 0;
#pragma unroll 8
    for (int d = 0; d < 64; ++d) {
      float tv = tok[g * 65 + d];
      aq += tv * wq[d];
      ak += tv * wk[d];
      av += tv * wv[d];
    }
    qs[g * 65 + e] = aq;
    ksm[g * 65 + e] = ak;
    vsm[g * 65 + e] = (f16)av;
  }
  __syncthreads();
  float* sc = tok;  // alias, tok dead
  for (int f0 = 0; f0 < 16; ++f0) {
    int f = p16 + f0;
    float s = 0;
#pragma unroll 8
    for (int e = 0; e < 64; ++e) s += qs[g * 65 + e] * ksm[f * 65 + e];
    sc[g * 65 + f] = s * 0.125f;
  }
  __syncthreads();
  if (tid < 64) {
    float m = -1e30f;
    for (int f = 0; f < 64; ++f) m = fmaxf(m, sc[tid * 65 + f]);
    float ssum = 0;
    for (int f = 0; f < 64; ++f) {
      float e = __expf(sc[tid * 65 + f] - m);
      sc[tid * 65 + f] = e;
      ssum += e;
    }
    float inv = 1.0f / ssum;
    for (int f = 0; f < 64; ++f) sc[tid * 65 + f] *= inv;
  }
  __syncthreads();
  // out_slice -> os LDS (overwrite ksm; dead after scores)
  float* os = ksm;
  for (int e0 = 0; e0 < 16; ++e0) {
    int e = p16 + e0;
    float o = 0;
#pragma unroll 8
    for (int f = 0; f < 64; ++f) o += sc[g * 65 + f] * (float)vsm[f * 65 + e];
    os[g * 65 + e] = o;
  }
  __syncthreads();
  // ---- PT fold (os from LDS)
  int o = tid >> 1, gh = (tid & 1) * 32;
  const float* wr = Wout + (size_t)o * 512 + h * 64;
  float wreg[64];
#pragma unroll
  for (int d = 0; d < 64; ++d) wreg[d] = wr[d];
  for (int gg = 0; gg < 32; ++gg) {
    int gI = gh + gg;
    float s = 0;
#pragma unroll
    for (int d = 0; d < 64; ++d) s += os[gI * 65 + d] * wreg[d];
    PT[(size_t)o * 512 + h * 64 + gI] = (f16)s;
  }
}

// -------------------- final: out[n,o] = sum_k W[n,k] * PT[o,k] + bout[o]
// R5 structure (32 KB LDS -> 5 blocks/CU; occupancy > pipelining for streaming).
__global__ __launch_bounds__(256, 2) void final_kernel(const f16* __restrict__ xmid,
                                                       const f16* __restrict__ PT,
                                                       const float* __restrict__ bout,
                                                       float* __restrict__ outb) {
  __shared__ f16 As[128 * 64];
  __shared__ f16 Bs[128 * 64];
  int tid = threadIdx.x;
  int tok0 = blockIdx.x << 7;        // 512 blocks
  int lane = tid & 63, wave = tid >> 6;
  int ln15 = lane & 15, quad = lane >> 4;
  int wm = wave & 1, wn = wave >> 1;
  int rr[4], qq8[4];
#pragma unroll
  for (int ph = 0; ph < 4; ++ph) {
    int s = ph * 256 + tid;
    rr[ph] = s >> 3;
    qq8[ph] = ((s & 7) ^ (rr[ph] & 7)) * 8;
  }
  int wbase = wave * 512;
  f32x4 acc[4][4] = {};
  const f16* aB = xmid + (size_t)tok0 * 512;
  const f16* bB = PT;
  for (int kc = 0; kc < 512; kc += 64) {
#pragma unroll
    for (int ph = 0; ph < 4; ++ph) {
      ldsdma16(&As[ph * 2048 + wbase], aB + (size_t)rr[ph] * 512 + kc + qq8[ph]);
      ldsdma16(&Bs[ph * 2048 + wbase], bB + (size_t)rr[ph] * 512 + kc + qq8[ph]);
    }
    __syncthreads();
#pragma unroll
    for (int ks = 0; ks < 2; ++ks) {
      f16x8 af[4], bfr[4];
      int q = ks * 4 + quad;
#pragma unroll
      for (int xx = 0; xx < 4; ++xx) {
        int ra = wm * 64 + xx * 16 + ln15;
        int rb = wn * 64 + xx * 16 + ln15;
        af[xx]  = *(const f16x8*)(&As[ra * 64 + (q ^ (ra & 7)) * 8]);
        bfr[xx] = *(const f16x8*)(&Bs[rb * 64 + (q ^ (rb & 7)) * 8]);
      }
#pragma unroll
      for (int mf = 0; mf < 4; ++mf)
#pragma unroll
        for (int nf = 0; nf < 4; ++nf)
          acc[mf][nf] = __builtin_amdgcn_mfma_f32_16x16x32_f16(af[mf], bfr[nf],
                                                               acc[mf][nf], 0, 0, 0);
    }
    __syncthreads();
  }
#pragma unroll
  for (int nf = 0; nf < 4; ++nf) {
    int col = wn * 64 + nf * 16 + ln15;
    float bo = bout[col];
#pragma unroll
    for (int mf = 0; mf < 4; ++mf) {
      int rbase = wm * 64 + mf * 16 + quad * 4;
#pragma unroll
      for (int v = 0; v < 4; ++v)
        outb[(size_t)(tok0 + rbase + v) * 128 + col] = acc[mf][nf][v] + bo;
    }
  }
}

extern "C" void kernel_launch(void* const* d_in, const int* in_sizes, int n_in,
                              void* d_out, int out_size, void* d_ws, size_t ws_size,
                              hipStream_t stream) {
  const float* x    = (const float*)d_in[0];
  const float* Wfx  = (const float*)d_in[1];
  const float* bfx  = (const float*)d_in[2];
  const float* Wx   = (const float*)d_in[3];
  const float* bx   = (const float*)d_in[4];
  const float* Wsl  = (const float*)d_in[5];
  const float* bsl  = (const float*)d_in[6];
  const float* temp = (const float*)d_in[7];
  const float* Wq   = (const float*)d_in[8];
  const float* Wk   = (const float*)d_in[9];
  const float* Wv   = (const float*)d_in[10];
  const float* Wout = (const float*)d_in[11];
  const float* bout = (const float*)d_in[12];
  float* out = (float*)d_out;
  char* ws = (char*)d_ws;

  f16*  padx = (f16*)(ws + OFF_PADX);
  f16*  wcat = (f16*)(ws + OFF_WCAT);
  float* ST  = (float*)(ws + OFF_ST);
  float* nrm = (float*)(ws + OFF_NORM);
  f16*  PT   = (f16*)(ws + OFF_PT);
  f16*  xmid = (f16*)(ws + OFF_XMID);
  f16*  fxT  = (f16*)(ws + OFF_FXT);

  prepw_kernel<<<4608, 256, 0, stream>>>(Wfx, Wx, wcat);
  for (int b = 0; b < 2; ++b) {
    const float* xb = x + (size_t)b * 65536 * 128;
    float* outb = out + (size_t)b * 65536 * 128;
    (void)hipMemsetAsync(ws + OFF_ST, 0, 131072 + 2048, stream);  // ST + norm
    pad_kernel<<<4161, 256, 0, stream>>>(xb, padx);
    conv_kernel<<<4096, 256, 0, stream>>>(padx, wcat, bfx, bx, xmid, fxT);
    slice_kernel<<<512, 256, 0, stream>>>(xmid, fxT, Wsl, bsl, temp, ST, nrm);
    attn_pt_kernel<<<8, 256, 0, stream>>>(ST, nrm, Wq, Wk, Wv, Wout, PT);
    final_kernel<<<512, 256, 0, stream>>>(xmid, PT, bout, outb);
  }
}